// Round 1
// baseline (2816.458 us; speedup 1.0000x reference)
//
#include <hip/hip_runtime.h>

// MultiDiffHeadAttention — fp32 correctness-first baseline.
// B=2, T=2048, E=1024, H=8 (diff heads), HS=64, 2HS=DO=128.
// mask = tril(ones, diagonal=1): position (t,s) allowed iff s <= t+1.
// Stages:
//   1) qkv_gemm x3 : X[4096,1024] @ W[h][1024][128] -> [B,H,T,128]
//   2) diff_attn   : two-stream online-softmax flash attention (fp32)
//   3) out_gemm    : ctx[4096,1024] @ Wp[1024,1024] + bp -> out

constexpr int Tn = 2048;
constexpr int En = 1024;
constexpr int Hn = 8;
constexpr float LAMBDA_INIT = 0.8f;

// ---------------- QKV projection GEMM ----------------
// grid (64, 16), block 256. 64x64 tile, K-tile 16, 4x4 per thread.
__global__ __launch_bounds__(256)
void qkv_gemm(const float* __restrict__ X, const float* __restrict__ W,
              float* __restrict__ out) {
  __shared__ __align__(16) float As[16][68];  // [k][m]
  __shared__ __align__(16) float Bs[16][68];  // [k][n]
  const int tid = threadIdx.x;
  const int m0 = blockIdx.x * 64;
  const int n0 = blockIdx.y * 64;
  const int h = n0 >> 7;          // head (n0 is multiple of 64; head width 128)
  const int dbase = n0 & 127;     // offset within head's 128 outputs
  const int mb = (tid >> 4) * 4;
  const int nb = (tid & 15) * 4;
  const int ac = tid & 15, ar0 = tid >> 4;
  const int bc = tid & 63, br0 = tid >> 6;
  const float* Wh = W + h * (En * 128) + dbase;
  float acc[4][4] = {};
  for (int k0 = 0; k0 < En; k0 += 16) {
#pragma unroll
    for (int p = 0; p < 4; ++p)
      As[ac][ar0 + p * 16] = X[(m0 + ar0 + p * 16) * En + k0 + ac];
#pragma unroll
    for (int p = 0; p < 4; ++p)
      Bs[br0 + p * 4][bc] = Wh[(k0 + br0 + p * 4) * 128 + bc];
    __syncthreads();
#pragma unroll
    for (int kk = 0; kk < 16; ++kk) {
      const float4 av = *(const float4*)&As[kk][mb];
      const float4 bv = *(const float4*)&Bs[kk][nb];
      const float a[4] = {av.x, av.y, av.z, av.w};
      const float b[4] = {bv.x, bv.y, bv.z, bv.w};
#pragma unroll
      for (int i = 0; i < 4; ++i)
#pragma unroll
        for (int j = 0; j < 4; ++j)
          acc[i][j] = fmaf(a[i], b[j], acc[i][j]);
    }
    __syncthreads();
  }
#pragma unroll
  for (int i = 0; i < 4; ++i) {
    const int m = m0 + mb + i;
    const int b = m >> 11;            // m = b*T + t
    const int t = m & (Tn - 1);
    float4 v = make_float4(acc[i][0], acc[i][1], acc[i][2], acc[i][3]);
    *(float4*)&out[((b * Hn + h) * Tn + t) * 128 + dbase + nb] = v;
  }
}

// ---------------- Output projection GEMM (+bias) ----------------
__global__ __launch_bounds__(256)
void out_gemm(const float* __restrict__ X, const float* __restrict__ W,
              const float* __restrict__ bias, float* __restrict__ out) {
  __shared__ __align__(16) float As[16][68];
  __shared__ __align__(16) float Bs[16][68];
  const int tid = threadIdx.x;
  const int m0 = blockIdx.x * 64;
  const int n0 = blockIdx.y * 64;
  const int mb = (tid >> 4) * 4;
  const int nb = (tid & 15) * 4;
  const int ac = tid & 15, ar0 = tid >> 4;
  const int bc = tid & 63, br0 = tid >> 6;
  float acc[4][4] = {};
  for (int k0 = 0; k0 < En; k0 += 16) {
#pragma unroll
    for (int p = 0; p < 4; ++p)
      As[ac][ar0 + p * 16] = X[(m0 + ar0 + p * 16) * En + k0 + ac];
#pragma unroll
    for (int p = 0; p < 4; ++p)
      Bs[br0 + p * 4][bc] = W[(k0 + br0 + p * 4) * En + n0 + bc];
    __syncthreads();
#pragma unroll
    for (int kk = 0; kk < 16; ++kk) {
      const float4 av = *(const float4*)&As[kk][mb];
      const float4 bv = *(const float4*)&Bs[kk][nb];
      const float a[4] = {av.x, av.y, av.z, av.w};
      const float b[4] = {bv.x, bv.y, bv.z, bv.w};
#pragma unroll
      for (int i = 0; i < 4; ++i)
#pragma unroll
        for (int j = 0; j < 4; ++j)
          acc[i][j] = fmaf(a[i], b[j], acc[i][j]);
    }
    __syncthreads();
  }
  const float4 bv4 = *(const float4*)&bias[n0 + nb];
#pragma unroll
  for (int i = 0; i < 4; ++i) {
    const int m = m0 + mb + i;
    float4 v = make_float4(acc[i][0] + bv4.x, acc[i][1] + bv4.y,
                           acc[i][2] + bv4.z, acc[i][3] + bv4.w);
    *(float4*)&out[m * En + n0 + nb] = v;
  }
}

// ---------------- Differential flash attention (fp32) ----------------
// grid (T/32, H, B), block 256. Q-tile 32 rows, K/V tiles 32.
// thread: r = tid>>3 (row 0..31), handles keys jb..jb+3 and out dims db..db+15.
__global__ __launch_bounds__(256)
void diff_attn(const float* __restrict__ Q, const float* __restrict__ K,
               const float* __restrict__ V,
               const float* __restrict__ lq1, const float* __restrict__ lk1,
               const float* __restrict__ lq2, const float* __restrict__ lk2,
               float* __restrict__ ctx) {
  __shared__ __align__(16) float Qs[32][132];
  __shared__ __align__(16) float Ks[32][132];
  __shared__ __align__(16) float Vs[32][132];
  __shared__ float P1[32][33];
  __shared__ float P2[32][33];

  const int qi = (int)gridDim.x - 1 - (int)blockIdx.x;  // heavy blocks first
  const int h = blockIdx.y;
  const int b = blockIdx.z;
  const int q0 = qi * 32;
  const int tid = threadIdx.x;
  const int basebh = ((b * Hn + h) * Tn) * 128;

  // lambda for this head (every thread computes it; trivially cheap)
  float lbd;
  {
    float d1 = 0.f, d2 = 0.f;
    for (int d = 0; d < 64; ++d) {
      d1 += lq1[h * 64 + d] * lk1[h * 64 + d];
      d2 += lq2[h * 64 + d] * lk2[h * 64 + d];
    }
    lbd = expf(d1) - expf(d2) + LAMBDA_INIT;
  }

  // stage Q tile
  for (int idx = tid; idx < 32 * 128; idx += 256) {
    const int rr = idx >> 7, d = idx & 127;
    Qs[rr][d] = Q[basebh + (q0 + rr) * 128 + d];
  }

  const int r = tid >> 3;          // my q row within tile
  const int jb = (tid & 7) * 4;    // my 4 keys within tile
  const int db = (tid & 7) * 16;   // my 16 output dims

  float m1 = -1e30f, l1 = 0.f, m2 = -1e30f, l2 = 0.f;
  float O1[16] = {}, O2[16] = {};

  const int nkt = min(qi + 2, Tn / 32);
  for (int kt = 0; kt < nkt; ++kt) {
    const int s0 = kt * 32;
    __syncthreads();  // previous PV done; Q staged (first iter)
    for (int idx = tid; idx < 32 * 128; idx += 256) {
      const int rr = idx >> 7, d = idx & 127;
      Ks[rr][d] = K[basebh + (s0 + rr) * 128 + d];
      Vs[rr][d] = V[basebh + (s0 + rr) * 128 + d];
    }
    __syncthreads();

    // ---- scores: two 64-dim dot products per (r, j) ----
    float s1v[4] = {0.f, 0.f, 0.f, 0.f}, s2v[4] = {0.f, 0.f, 0.f, 0.f};
#pragma unroll
    for (int d4 = 0; d4 < 16; ++d4) {
      const float4 qv = *(const float4*)&Qs[r][d4 * 4];
#pragma unroll
      for (int jj = 0; jj < 4; ++jj) {
        const float4 kv = *(const float4*)&Ks[jb + jj][d4 * 4];
        s1v[jj] = fmaf(qv.x, kv.x, s1v[jj]);
        s1v[jj] = fmaf(qv.y, kv.y, s1v[jj]);
        s1v[jj] = fmaf(qv.z, kv.z, s1v[jj]);
        s1v[jj] = fmaf(qv.w, kv.w, s1v[jj]);
      }
    }
#pragma unroll
    for (int d4 = 16; d4 < 32; ++d4) {
      const float4 qv = *(const float4*)&Qs[r][d4 * 4];
#pragma unroll
      for (int jj = 0; jj < 4; ++jj) {
        const float4 kv = *(const float4*)&Ks[jb + jj][d4 * 4];
        s2v[jj] = fmaf(qv.x, kv.x, s2v[jj]);
        s2v[jj] = fmaf(qv.y, kv.y, s2v[jj]);
        s2v[jj] = fmaf(qv.z, kv.z, s2v[jj]);
        s2v[jj] = fmaf(qv.w, kv.w, s2v[jj]);
      }
    }
    const int tg = q0 + r;
#pragma unroll
    for (int jj = 0; jj < 4; ++jj) {
      const int sg = s0 + jb + jj;
      if (sg <= tg + 1) { s1v[jj] *= 0.125f; s2v[jj] *= 0.125f; }
      else              { s1v[jj] = -1e30f;  s2v[jj] = -1e30f; }
    }

    // ---- online softmax (row = 8 consecutive lanes) ----
    float mt1 = fmaxf(fmaxf(s1v[0], s1v[1]), fmaxf(s1v[2], s1v[3]));
    float mt2 = fmaxf(fmaxf(s2v[0], s2v[1]), fmaxf(s2v[2], s2v[3]));
#pragma unroll
    for (int off = 1; off <= 4; off <<= 1) {
      mt1 = fmaxf(mt1, __shfl_xor(mt1, off));
      mt2 = fmaxf(mt2, __shfl_xor(mt2, off));
    }
    const float m1n = fmaxf(m1, mt1), m2n = fmaxf(m2, mt2);
    float p1[4], p2[4];
    float rs1 = 0.f, rs2 = 0.f;
#pragma unroll
    for (int jj = 0; jj < 4; ++jj) {
      p1[jj] = __expf(s1v[jj] - m1n);
      p2[jj] = __expf(s2v[jj] - m2n);
      rs1 += p1[jj]; rs2 += p2[jj];
    }
#pragma unroll
    for (int off = 1; off <= 4; off <<= 1) {
      rs1 += __shfl_xor(rs1, off);
      rs2 += __shfl_xor(rs2, off);
    }
    const float f1 = __expf(m1 - m1n), f2 = __expf(m2 - m2n);
    l1 = l1 * f1 + rs1; l2 = l2 * f2 + rs2;
    m1 = m1n; m2 = m2n;
#pragma unroll
    for (int i = 0; i < 16; ++i) { O1[i] *= f1; O2[i] *= f2; }
#pragma unroll
    for (int jj = 0; jj < 4; ++jj) {
      P1[r][jb + jj] = p1[jj];
      P2[r][jb + jj] = p2[jj];
    }
    __syncthreads();

    // ---- PV accumulate ----
#pragma unroll 8
    for (int j = 0; j < 32; ++j) {
      const float w1 = P1[r][j];
      const float w2 = P2[r][j];
#pragma unroll
      for (int i4 = 0; i4 < 4; ++i4) {
        const float4 vv = *(const float4*)&Vs[j][db + i4 * 4];
        O1[i4 * 4 + 0] = fmaf(w1, vv.x, O1[i4 * 4 + 0]);
        O1[i4 * 4 + 1] = fmaf(w1, vv.y, O1[i4 * 4 + 1]);
        O1[i4 * 4 + 2] = fmaf(w1, vv.z, O1[i4 * 4 + 2]);
        O1[i4 * 4 + 3] = fmaf(w1, vv.w, O1[i4 * 4 + 3]);
        O2[i4 * 4 + 0] = fmaf(w2, vv.x, O2[i4 * 4 + 0]);
        O2[i4 * 4 + 1] = fmaf(w2, vv.y, O2[i4 * 4 + 1]);
        O2[i4 * 4 + 2] = fmaf(w2, vv.z, O2[i4 * 4 + 2]);
        O2[i4 * 4 + 3] = fmaf(w2, vv.w, O2[i4 * 4 + 3]);
      }
    }
  }

  // epilogue: ctx = 0.2*(O1/l1 - lbd*O2/l2), layout [B,T,H*128]
  const float inv1 = 1.0f / l1, inv2 = 1.0f / l2;
  const float c1 = (1.0f - LAMBDA_INIT) * inv1;
  const float c2 = (1.0f - LAMBDA_INIT) * lbd * inv2;
  const int t = q0 + r;
  float* dst = &ctx[(b * Tn + t) * En + h * 128 + db];
#pragma unroll
  for (int i4 = 0; i4 < 4; ++i4) {
    float4 o;
    o.x = c1 * O1[i4 * 4 + 0] - c2 * O2[i4 * 4 + 0];
    o.y = c1 * O1[i4 * 4 + 1] - c2 * O2[i4 * 4 + 1];
    o.z = c1 * O1[i4 * 4 + 2] - c2 * O2[i4 * 4 + 2];
    o.w = c1 * O1[i4 * 4 + 3] - c2 * O2[i4 * 4 + 3];
    *(float4*)&dst[i4 * 4] = o;
  }
}

extern "C" void kernel_launch(void* const* d_in, const int* in_sizes, int n_in,
                              void* d_out, int out_size, void* d_ws, size_t ws_size,
                              hipStream_t stream) {
  const float* q   = (const float*)d_in[0];
  const float* k   = (const float*)d_in[1];
  const float* v   = (const float*)d_in[2];
  const float* Wq  = (const float*)d_in[3];
  const float* Wk  = (const float*)d_in[4];
  const float* Wv  = (const float*)d_in[5];
  const float* lq1 = (const float*)d_in[6];
  const float* lk1 = (const float*)d_in[7];
  const float* lq2 = (const float*)d_in[8];
  const float* lk2 = (const float*)d_in[9];
  const float* Wp  = (const float*)d_in[10];
  const float* bp  = (const float*)d_in[11];
  // d_in[12] (mask) is deterministic tril(+1): computed inline.

  float* ws = (float*)d_ws;
  const size_t SZ = (size_t)2 * Hn * Tn * 128;  // 4,194,304 floats
  float* Qb  = ws;
  float* Kb  = ws + SZ;
  float* Vb  = ws + 2 * SZ;
  float* ctx = ws + 3 * SZ;

  dim3 blk(256);
  qkv_gemm<<<dim3(64, 16), blk, 0, stream>>>(q, Wq, Qb);
  qkv_gemm<<<dim3(64, 16), blk, 0, stream>>>(k, Wk, Kb);
  qkv_gemm<<<dim3(64, 16), blk, 0, stream>>>(v, Wv, Vb);
  diff_attn<<<dim3(Tn / 32, Hn, 2), blk, 0, stream>>>(Qb, Kb, Vb,
                                                      lq1, lk1, lq2, lk2, ctx);
  out_gemm<<<dim3(64, 16), blk, 0, stream>>>(ctx, Wp, bp, (float*)d_out);
}

// Round 2
// 1293.293 us; speedup vs baseline: 2.1777x; 2.1777x over previous
//
#include <hip/hip_runtime.h>
#include <hip/hip_bf16.h>

// MultiDiffHeadAttention. B=2, T=2048, E=1024, H=8, HS=64, DO=128.
// mask = tril(ones, diagonal=1): (t,s) allowed iff s <= t+1.
// R1: bf16-MFMA projections + restructured fp32 flash attention
//     (conflict-free LDS, 3 blocks/CU occupancy, shfl-based P exchange).

constexpr int Tn = 2048;
constexpr int En = 1024;
constexpr int Hn = 8;
constexpr float LAMBDA_INIT = 0.8f;

typedef __attribute__((ext_vector_type(8))) short short8;
typedef __attribute__((ext_vector_type(4))) float f32x4;

__device__ __forceinline__ short f2bf(float x) {
  union { __hip_bfloat16 h; short s; } u;
  u.h = __float2bfloat16(x);
  return u.s;
}

// ---------------- QKV projection: bf16 MFMA ----------------
// grid (32, 8, 3), block 256 (4 waves). 128x128 tile (N-tile = one head),
// BK=32, wave quadrant 64x64 = 4x4 frags of 16x16x32.
__global__ __launch_bounds__(256)
void qkv_mfma(const float* __restrict__ q, const float* __restrict__ k,
              const float* __restrict__ v,
              const float* __restrict__ Wq, const float* __restrict__ Wk,
              const float* __restrict__ Wv,
              float* __restrict__ Qo, float* __restrict__ Ko,
              float* __restrict__ Vo) {
  __shared__ short As[128 * 32];
  __shared__ short Bs[128 * 32];  // stored [n][k]
  const int which = blockIdx.z;
  const float* X = (which == 0) ? q : (which == 1) ? k : v;
  const float* W = (which == 0) ? Wq : (which == 1) ? Wk : Wv;
  float* Out = (which == 0) ? Qo : (which == 1) ? Ko : Vo;
  const int head = blockIdx.y;
  const int m0 = blockIdx.x * 128;
  const float* Wh = W + (size_t)head * En * 128;

  const int tid = threadIdx.x;
  const int lane = tid & 63;
  const int w = tid >> 6, wr = w >> 1, wc = w & 1;
  const int fr = lane & 15, fk = (lane >> 4) * 8;
  const int arow = tid >> 1, ah = (tid & 1) * 16;  // A stage: 16 k per thread
  const int bn = tid & 127, bkg = (tid >> 7) * 16; // B stage: 16 k per thread

  f32x4 acc[4][4] = {};

  for (int k0 = 0; k0 < En; k0 += 32) {
    // global loads (before barrier, hides latency under the wait)
    float4 xa[4];
#pragma unroll
    for (int qq = 0; qq < 4; ++qq)
      xa[qq] = *(const float4*)&X[(size_t)(m0 + arow) * En + k0 + ah + qq * 4];
    float xb[16];
#pragma unroll
    for (int j = 0; j < 16; ++j)
      xb[j] = Wh[(size_t)(k0 + bkg + j) * 128 + bn];

    __syncthreads();  // everyone done reading LDS from prev iter
    short8 pa0, pa1;
#pragma unroll
    for (int e = 0; e < 4; ++e) {
      pa0[e]     = f2bf(((const float*)&xa[0])[e]);
      pa0[e + 4] = f2bf(((const float*)&xa[1])[e]);
      pa1[e]     = f2bf(((const float*)&xa[2])[e]);
      pa1[e + 4] = f2bf(((const float*)&xa[3])[e]);
    }
    *(short8*)&As[arow * 32 + ah] = pa0;
    *(short8*)&As[arow * 32 + ah + 8] = pa1;
    short8 pb0, pb1;
#pragma unroll
    for (int e = 0; e < 8; ++e) {
      pb0[e] = f2bf(xb[e]);
      pb1[e] = f2bf(xb[e + 8]);
    }
    *(short8*)&Bs[bn * 32 + bkg] = pb0;
    *(short8*)&Bs[bn * 32 + bkg + 8] = pb1;
    __syncthreads();

    short8 a[4], b[4];
#pragma unroll
    for (int i = 0; i < 4; ++i)
      a[i] = *(const short8*)&As[(wr * 64 + i * 16 + fr) * 32 + fk];
#pragma unroll
    for (int j = 0; j < 4; ++j)
      b[j] = *(const short8*)&Bs[(wc * 64 + j * 16 + fr) * 32 + fk];
#pragma unroll
    for (int i = 0; i < 4; ++i)
#pragma unroll
      for (int j = 0; j < 4; ++j)
        acc[i][j] = __builtin_amdgcn_mfma_f32_16x16x32_bf16(a[i], b[j],
                                                            acc[i][j], 0, 0, 0);
  }

  // epilogue: C/D layout col=lane&15, row=(lane>>4)*4+p  [HW-verified]
  const int crow = (lane >> 4) * 4, ccol = lane & 15;
#pragma unroll
  for (int i = 0; i < 4; ++i) {
    const int m = m0 + wr * 64 + i * 16 + crow;
    const int bb = m >> 11, t = m & (Tn - 1);
    float* dst = &Out[(((size_t)bb * Hn + head) * Tn + t) * 128];
#pragma unroll
    for (int j = 0; j < 4; ++j) {
      const int d = wc * 64 + j * 16 + ccol;
#pragma unroll
      for (int p = 0; p < 4; ++p)
        dst[(size_t)p * 128 + d] = acc[i][j][p];
    }
  }
}

// ---------------- Output projection: bf16 MFMA + bias ----------------
// grid (32, 8), block 256. Same structure; B from Wp[1024][1024].
__global__ __launch_bounds__(256)
void proj_mfma(const float* __restrict__ X, const float* __restrict__ W,
               const float* __restrict__ bias, float* __restrict__ Out) {
  __shared__ short As[128 * 32];
  __shared__ short Bs[128 * 32];
  const int m0 = blockIdx.x * 128;
  const int n0 = blockIdx.y * 128;

  const int tid = threadIdx.x;
  const int lane = tid & 63;
  const int w = tid >> 6, wr = w >> 1, wc = w & 1;
  const int fr = lane & 15, fk = (lane >> 4) * 8;
  const int arow = tid >> 1, ah = (tid & 1) * 16;
  const int bn = tid & 127, bkg = (tid >> 7) * 16;

  f32x4 acc[4][4] = {};

  for (int k0 = 0; k0 < En; k0 += 32) {
    float4 xa[4];
#pragma unroll
    for (int qq = 0; qq < 4; ++qq)
      xa[qq] = *(const float4*)&X[(size_t)(m0 + arow) * En + k0 + ah + qq * 4];
    float xb[16];
#pragma unroll
    for (int j = 0; j < 16; ++j)
      xb[j] = W[(size_t)(k0 + bkg + j) * En + n0 + bn];

    __syncthreads();
    short8 pa0, pa1;
#pragma unroll
    for (int e = 0; e < 4; ++e) {
      pa0[e]     = f2bf(((const float*)&xa[0])[e]);
      pa0[e + 4] = f2bf(((const float*)&xa[1])[e]);
      pa1[e]     = f2bf(((const float*)&xa[2])[e]);
      pa1[e + 4] = f2bf(((const float*)&xa[3])[e]);
    }
    *(short8*)&As[arow * 32 + ah] = pa0;
    *(short8*)&As[arow * 32 + ah + 8] = pa1;
    short8 pb0, pb1;
#pragma unroll
    for (int e = 0; e < 8; ++e) {
      pb0[e] = f2bf(xb[e]);
      pb1[e] = f2bf(xb[e + 8]);
    }
    *(short8*)&Bs[bn * 32 + bkg] = pb0;
    *(short8*)&Bs[bn * 32 + bkg + 8] = pb1;
    __syncthreads();

    short8 a[4], b[4];
#pragma unroll
    for (int i = 0; i < 4; ++i)
      a[i] = *(const short8*)&As[(wr * 64 + i * 16 + fr) * 32 + fk];
#pragma unroll
    for (int j = 0; j < 4; ++j)
      b[j] = *(const short8*)&Bs[(wc * 64 + j * 16 + fr) * 32 + fk];
#pragma unroll
    for (int i = 0; i < 4; ++i)
#pragma unroll
      for (int j = 0; j < 4; ++j)
        acc[i][j] = __builtin_amdgcn_mfma_f32_16x16x32_bf16(a[i], b[j],
                                                            acc[i][j], 0, 0, 0);
  }

  const int crow = (lane >> 4) * 4, ccol = lane & 15;
#pragma unroll
  for (int i = 0; i < 4; ++i) {
    const int m = m0 + wr * 64 + i * 16 + crow;
#pragma unroll
    for (int j = 0; j < 4; ++j) {
      const int n = n0 + wc * 64 + j * 16 + ccol;
      const float bv = bias[n];
#pragma unroll
      for (int p = 0; p < 4; ++p)
        Out[(size_t)(m + p) * En + n] = acc[i][j][p] + bv;
    }
  }
}

// ---------------- Differential flash attention (fp32, restructured) ----
// grid (T/32, H, B), block 256 (4 waves). Q-tile 32 rows, K-tile 32.
// Thread (r = tid>>3, c = tid&7): q-row r; score keys {c+8*jj};
// PV/output dims {8c..8c+7} u {64+8c..64+8c+7}.
// K LDS is 16B-chunk XOR-swizzled (chunk ^= row&7) -> conflict-free reads.
__global__ __launch_bounds__(256)
void diff_attn2(const float* __restrict__ Q, const float* __restrict__ K,
                const float* __restrict__ V,
                const float* __restrict__ lq1, const float* __restrict__ lk1,
                const float* __restrict__ lq2, const float* __restrict__ lk2,
                float* __restrict__ ctx) {
  __shared__ __align__(16) float Qs[32 * 132];
  __shared__ __align__(16) float Ks[32 * 128];
  __shared__ __align__(16) float Vs[32 * 128];

  const int qi = (int)gridDim.x - 1 - (int)blockIdx.x;  // heavy blocks first
  const int h = blockIdx.y;
  const int b = blockIdx.z;
  const int q0 = qi * 32;
  const int tid = threadIdx.x;
  const int r = tid >> 3, c = tid & 7;
  const size_t basebh = ((size_t)(b * Hn + h)) * Tn * 128;

  float lbd;
  {
    float d1 = 0.f, d2 = 0.f;
    for (int d = 0; d < 64; ++d) {
      d1 += lq1[h * 64 + d] * lk1[h * 64 + d];
      d2 += lq2[h * 64 + d] * lk2[h * 64 + d];
    }
    lbd = __expf(d1) - __expf(d2) + LAMBDA_INIT;
  }

  // stage Q tile once
  {
    const float* Qg = Q + basebh + (size_t)q0 * 128;
#pragma unroll
    for (int qq = 0; qq < 4; ++qq)
      *(float4*)&Qs[r * 132 + c * 16 + qq * 4] =
          *(const float4*)&Qg[r * 128 + c * 16 + qq * 4];
  }

  float m1 = -1e30f, l1 = 0.f, m2 = -1e30f, l2 = 0.f;
  float O1[16] = {}, O2[16] = {};
  const int tg = q0 + r;

  const int nkt = min(qi + 2, Tn / 32);
  for (int kt = 0; kt < nkt; ++kt) {
    const int s0 = kt * 32;
    const float* Kg = K + basebh + (size_t)s0 * 128;
    const float* Vg = V + basebh + (size_t)s0 * 128;
    __syncthreads();  // prev tile's reads done (also covers Q on kt=0)
    // K: swizzled 16B chunks; V: linear
#pragma unroll
    for (int qq = 0; qq < 4; ++qq) {
      float4 x = *(const float4*)&Kg[r * 128 + c * 16 + qq * 4];
      const int ch = (c * 4 + qq) ^ (r & 7);
      *(float4*)&Ks[r * 128 + ch * 4] = x;
    }
    *(float4*)&Vs[r * 128 + c * 8] = *(const float4*)&Vg[r * 128 + c * 8];
    *(float4*)&Vs[r * 128 + c * 8 + 4] =
        *(const float4*)&Vg[r * 128 + c * 8 + 4];
    *(float4*)&Vs[r * 128 + 64 + c * 8] =
        *(const float4*)&Vg[r * 128 + 64 + c * 8];
    *(float4*)&Vs[r * 128 + 64 + c * 8 + 4] =
        *(const float4*)&Vg[r * 128 + 64 + c * 8 + 4];
    __syncthreads();

    // ---- scores: keys c+8*jj; stream1 dims 0..63, stream2 dims 64..127
    float s1v[4] = {0.f, 0.f, 0.f, 0.f}, s2v[4] = {0.f, 0.f, 0.f, 0.f};
#pragma unroll
    for (int d4 = 0; d4 < 16; ++d4) {
      const float4 qv = *(const float4*)&Qs[r * 132 + d4 * 4];
#pragma unroll
      for (int jj = 0; jj < 4; ++jj) {
        const int row = c + 8 * jj;
        const float4 kv = *(const float4*)&Ks[row * 128 + ((d4 ^ c) << 2)];
        s1v[jj] = fmaf(qv.x, kv.x, s1v[jj]);
        s1v[jj] = fmaf(qv.y, kv.y, s1v[jj]);
        s1v[jj] = fmaf(qv.z, kv.z, s1v[jj]);
        s1v[jj] = fmaf(qv.w, kv.w, s1v[jj]);
      }
    }
#pragma unroll
    for (int d4 = 16; d4 < 32; ++d4) {
      const float4 qv = *(const float4*)&Qs[r * 132 + d4 * 4];
#pragma unroll
      for (int jj = 0; jj < 4; ++jj) {
        const int row = c + 8 * jj;
        const float4 kv = *(const float4*)&Ks[row * 128 + ((d4 ^ c) << 2)];
        s2v[jj] = fmaf(qv.x, kv.x, s2v[jj]);
        s2v[jj] = fmaf(qv.y, kv.y, s2v[jj]);
        s2v[jj] = fmaf(qv.z, kv.z, s2v[jj]);
        s2v[jj] = fmaf(qv.w, kv.w, s2v[jj]);
      }
    }
#pragma unroll
    for (int jj = 0; jj < 4; ++jj) {
      const int sg = s0 + c + 8 * jj;
      if (sg <= tg + 1) { s1v[jj] *= 0.125f; s2v[jj] *= 0.125f; }
      else              { s1v[jj] = -1e30f;  s2v[jj] = -1e30f; }
    }

    // ---- online softmax across the 8 c-lanes of this row
    float mt1 = fmaxf(fmaxf(s1v[0], s1v[1]), fmaxf(s1v[2], s1v[3]));
    float mt2 = fmaxf(fmaxf(s2v[0], s2v[1]), fmaxf(s2v[2], s2v[3]));
#pragma unroll
    for (int off = 1; off <= 4; off <<= 1) {
      mt1 = fmaxf(mt1, __shfl_xor(mt1, off));
      mt2 = fmaxf(mt2, __shfl_xor(mt2, off));
    }
    const float m1n = fmaxf(m1, mt1), m2n = fmaxf(m2, mt2);
    float p1[4], p2[4], rs1 = 0.f, rs2 = 0.f;
#pragma unroll
    for (int jj = 0; jj < 4; ++jj) {
      p1[jj] = __expf(s1v[jj] - m1n);
      p2[jj] = __expf(s2v[jj] - m2n);
      rs1 += p1[jj]; rs2 += p2[jj];
    }
#pragma unroll
    for (int off = 1; off <= 4; off <<= 1) {
      rs1 += __shfl_xor(rs1, off);
      rs2 += __shfl_xor(rs2, off);
    }
    const float f1 = __expf(m1 - m1n), f2 = __expf(m2 - m2n);
    l1 = l1 * f1 + rs1; l2 = l2 * f2 + rs2;
    m1 = m1n; m2 = m2n;
#pragma unroll
    for (int i = 0; i < 16; ++i) { O1[i] *= f1; O2[i] *= f2; }

    // ---- PV: p exchanged via shfl within the 8-lane row group
    const int grp = tid & 56;
#pragma unroll
    for (int jj = 0; jj < 4; ++jj) {
#pragma unroll
      for (int js = 0; js < 8; ++js) {
        const float w1 = __shfl(p1[jj], grp | js);
        const float w2 = __shfl(p2[jj], grp | js);
        const int j = jj * 8 + js;
        const float4 va = *(const float4*)&Vs[j * 128 + c * 8];
        const float4 vb = *(const float4*)&Vs[j * 128 + c * 8 + 4];
        const float4 vc = *(const float4*)&Vs[j * 128 + 64 + c * 8];
        const float4 vd = *(const float4*)&Vs[j * 128 + 64 + c * 8 + 4];
        O1[0] = fmaf(w1, va.x, O1[0]);   O2[0] = fmaf(w2, va.x, O2[0]);
        O1[1] = fmaf(w1, va.y, O1[1]);   O2[1] = fmaf(w2, va.y, O2[1]);
        O1[2] = fmaf(w1, va.z, O1[2]);   O2[2] = fmaf(w2, va.z, O2[2]);
        O1[3] = fmaf(w1, va.w, O1[3]);   O2[3] = fmaf(w2, va.w, O2[3]);
        O1[4] = fmaf(w1, vb.x, O1[4]);   O2[4] = fmaf(w2, vb.x, O2[4]);
        O1[5] = fmaf(w1, vb.y, O1[5]);   O2[5] = fmaf(w2, vb.y, O2[5]);
        O1[6] = fmaf(w1, vb.z, O1[6]);   O2[6] = fmaf(w2, vb.z, O2[6]);
        O1[7] = fmaf(w1, vb.w, O1[7]);   O2[7] = fmaf(w2, vb.w, O2[7]);
        O1[8] = fmaf(w1, vc.x, O1[8]);   O2[8] = fmaf(w2, vc.x, O2[8]);
        O1[9] = fmaf(w1, vc.y, O1[9]);   O2[9] = fmaf(w2, vc.y, O2[9]);
        O1[10] = fmaf(w1, vc.z, O1[10]); O2[10] = fmaf(w2, vc.z, O2[10]);
        O1[11] = fmaf(w1, vc.w, O1[11]); O2[11] = fmaf(w2, vc.w, O2[11]);
        O1[12] = fmaf(w1, vd.x, O1[12]); O2[12] = fmaf(w2, vd.x, O2[12]);
        O1[13] = fmaf(w1, vd.y, O1[13]); O2[13] = fmaf(w2, vd.y, O2[13]);
        O1[14] = fmaf(w1, vd.z, O1[14]); O2[14] = fmaf(w2, vd.z, O2[14]);
        O1[15] = fmaf(w1, vd.w, O1[15]); O2[15] = fmaf(w2, vd.w, O2[15]);
      }
    }
  }

  // epilogue: ctx = 0.2*(O1/l1 - lbd*O2/l2), layout [B,T,H*128]
  const float c1 = (1.0f - LAMBDA_INIT) / l1;
  const float c2 = (1.0f - LAMBDA_INIT) * lbd / l2;
  float* dst = &ctx[((size_t)b * Tn + tg) * En + h * 128];
  float4 o;
#pragma unroll
  for (int g = 0; g < 4; ++g) {
    o.x = c1 * O1[g * 4 + 0] - c2 * O2[g * 4 + 0];
    o.y = c1 * O1[g * 4 + 1] - c2 * O2[g * 4 + 1];
    o.z = c1 * O1[g * 4 + 2] - c2 * O2[g * 4 + 2];
    o.w = c1 * O1[g * 4 + 3] - c2 * O2[g * 4 + 3];
    const int off = (g < 2) ? (c * 8 + g * 4) : (64 + c * 8 + (g - 2) * 4);
    *(float4*)&dst[off] = o;
  }
}

extern "C" void kernel_launch(void* const* d_in, const int* in_sizes, int n_in,
                              void* d_out, int out_size, void* d_ws, size_t ws_size,
                              hipStream_t stream) {
  const float* q   = (const float*)d_in[0];
  const float* k   = (const float*)d_in[1];
  const float* v   = (const float*)d_in[2];
  const float* Wq  = (const float*)d_in[3];
  const float* Wk  = (const float*)d_in[4];
  const float* Wv  = (const float*)d_in[5];
  const float* lq1 = (const float*)d_in[6];
  const float* lk1 = (const float*)d_in[7];
  const float* lq2 = (const float*)d_in[8];
  const float* lk2 = (const float*)d_in[9];
  const float* Wp  = (const float*)d_in[10];
  const float* bp  = (const float*)d_in[11];

  float* ws = (float*)d_ws;
  const size_t SZ = (size_t)2 * Hn * Tn * 128;  // 4,194,304 floats
  float* Qb  = ws;
  float* Kb  = ws + SZ;
  float* Vb  = ws + 2 * SZ;
  float* ctx = ws + 3 * SZ;

  dim3 blk(256);
  qkv_mfma<<<dim3(32, 8, 3), blk, 0, stream>>>(q, k, v, Wq, Wk, Wv, Qb, Kb, Vb);
  diff_attn2<<<dim3(Tn / 32, Hn, 2), blk, 0, stream>>>(Qb, Kb, Vb,
                                                       lq1, lk1, lq2, lk2, ctx);
  proj_mfma<<<dim3(32, 8), blk, 0, stream>>>(ctx, Wp, bp, (float*)d_out);
}

// Round 3
// 295.305 us; speedup vs baseline: 9.5374x; 4.3795x over previous
//
#include <hip/hip_runtime.h>
#include <hip/hip_bf16.h>

// MultiDiffHeadAttention. B=2, T=2048, E=1024, H=8, HS=64, DO=128.
// mask = tril(ones, diagonal=1): (t,s) allowed iff s <= t+1.
// R2: full bf16 MFMA pipeline. Projections emit bf16 Q,K [b,h,t,128],
// transposed V [b,h,d,T], attention is MFMA flash (QK^T + O^T = V^T P),
// ctx bf16, final projection bf16-A MFMA.

constexpr int Tn = 2048;
constexpr int En = 1024;
constexpr int Hn = 8;
constexpr float LAMBDA_INIT = 0.8f;

typedef __attribute__((ext_vector_type(8))) short short8;
typedef __attribute__((ext_vector_type(4))) short s16x4;
typedef __attribute__((ext_vector_type(4))) float f32x4;

__device__ __forceinline__ short f2bf(float x) {
  union { __hip_bfloat16 h; short s; } u;
  u.h = __float2bfloat16(x);
  return u.s;
}
__device__ __forceinline__ float bf2f(short s) {
  union { float f; unsigned u; } u;
  u.u = ((unsigned)(unsigned short)s) << 16;
  return u.f;
}

// ---------------- QKV projection: bf16 MFMA ----------------
// grid (32, 8, 3), block 256 (4 waves). 128x128 tile (N-tile = one head).
// Outputs: Q,K bf16 [b][h][t][128]; V bf16 TRANSPOSED [b][h][d][T].
__global__ __launch_bounds__(256)
void qkv_mfma(const float* __restrict__ q, const float* __restrict__ k,
              const float* __restrict__ v,
              const float* __restrict__ Wq, const float* __restrict__ Wk,
              const float* __restrict__ Wv,
              short* __restrict__ Qo, short* __restrict__ Ko,
              short* __restrict__ Vto) {
  __shared__ short As[128 * 32];
  __shared__ short Bs[128 * 32];  // stored [n][k]
  const int which = blockIdx.z;
  const float* X = (which == 0) ? q : (which == 1) ? k : v;
  const float* W = (which == 0) ? Wq : (which == 1) ? Wk : Wv;
  const int head = blockIdx.y;
  const int m0 = blockIdx.x * 128;
  const float* Wh = W + (size_t)head * En * 128;

  const int tid = threadIdx.x;
  const int lane = tid & 63;
  const int w = tid >> 6, wr = w >> 1, wc = w & 1;
  const int fr = lane & 15, fk = (lane >> 4) * 8;
  const int arow = tid >> 1, ah = (tid & 1) * 16;
  const int bn = tid & 127, bkg = (tid >> 7) * 16;

  f32x4 acc[4][4] = {};

  for (int k0 = 0; k0 < En; k0 += 32) {
    float4 xa[4];
#pragma unroll
    for (int qq = 0; qq < 4; ++qq)
      xa[qq] = *(const float4*)&X[(size_t)(m0 + arow) * En + k0 + ah + qq * 4];
    float xb[16];
#pragma unroll
    for (int j = 0; j < 16; ++j)
      xb[j] = Wh[(size_t)(k0 + bkg + j) * 128 + bn];

    __syncthreads();
    short8 pa0, pa1;
#pragma unroll
    for (int e = 0; e < 4; ++e) {
      pa0[e]     = f2bf(((const float*)&xa[0])[e]);
      pa0[e + 4] = f2bf(((const float*)&xa[1])[e]);
      pa1[e]     = f2bf(((const float*)&xa[2])[e]);
      pa1[e + 4] = f2bf(((const float*)&xa[3])[e]);
    }
    *(short8*)&As[arow * 32 + ah] = pa0;
    *(short8*)&As[arow * 32 + ah + 8] = pa1;
    short8 pb0, pb1;
#pragma unroll
    for (int e = 0; e < 8; ++e) {
      pb0[e] = f2bf(xb[e]);
      pb1[e] = f2bf(xb[e + 8]);
    }
    *(short8*)&Bs[bn * 32 + bkg] = pb0;
    *(short8*)&Bs[bn * 32 + bkg + 8] = pb1;
    __syncthreads();

    short8 a[4], b[4];
#pragma unroll
    for (int i = 0; i < 4; ++i)
      a[i] = *(const short8*)&As[(wr * 64 + i * 16 + fr) * 32 + fk];
#pragma unroll
    for (int j = 0; j < 4; ++j)
      b[j] = *(const short8*)&Bs[(wc * 64 + j * 16 + fr) * 32 + fk];
#pragma unroll
    for (int i = 0; i < 4; ++i)
#pragma unroll
      for (int j = 0; j < 4; ++j)
        acc[i][j] = __builtin_amdgcn_mfma_f32_16x16x32_bf16(a[i], b[j],
                                                            acc[i][j], 0, 0, 0);
  }

  const int crow = (lane >> 4) * 4, ccol = lane & 15;
  if (which == 2) {
    // V: transposed store, 4 consecutive t packed per 8B
#pragma unroll
    for (int i = 0; i < 4; ++i) {
      const int m = m0 + wr * 64 + i * 16 + crow;
      const int bb = m >> 11, t = m & (Tn - 1);
#pragma unroll
      for (int j = 0; j < 4; ++j) {
        const int d = wc * 64 + j * 16 + ccol;
        s16x4 pk;
#pragma unroll
        for (int p = 0; p < 4; ++p) pk[p] = f2bf(acc[i][j][p]);
        *(s16x4*)&Vto[((size_t)(bb * Hn + head) * 128 + d) * Tn + t] = pk;
      }
    }
  } else {
    short* Out = (which == 0) ? Qo : Ko;
#pragma unroll
    for (int i = 0; i < 4; ++i) {
      const int m = m0 + wr * 64 + i * 16 + crow;
      const int bb = m >> 11, t = m & (Tn - 1);
      short* dst = Out + ((size_t)(bb * Hn + head) * Tn + t) * 128;
#pragma unroll
      for (int j = 0; j < 4; ++j) {
        const int d = wc * 64 + j * 16 + ccol;
#pragma unroll
        for (int p = 0; p < 4; ++p)
          dst[(size_t)p * 128 + d] = f2bf(acc[i][j][p]);
      }
    }
  }
}

// ---------------- Output projection: bf16-A MFMA + bias ----------------
__global__ __launch_bounds__(256)
void proj_mfma(const short* __restrict__ Xb, const float* __restrict__ W,
               const float* __restrict__ bias, float* __restrict__ Out) {
  __shared__ short As[128 * 32];
  __shared__ short Bs[128 * 32];
  const int m0 = blockIdx.x * 128;
  const int n0 = blockIdx.y * 128;

  const int tid = threadIdx.x;
  const int lane = tid & 63;
  const int w = tid >> 6, wr = w >> 1, wc = w & 1;
  const int fr = lane & 15, fk = (lane >> 4) * 8;
  const int arow = tid >> 1, ah = (tid & 1) * 16;
  const int bn = tid & 127, bkg = (tid >> 7) * 16;

  f32x4 acc[4][4] = {};

  for (int k0 = 0; k0 < En; k0 += 32) {
    short8 xa0 = *(const short8*)&Xb[(size_t)(m0 + arow) * En + k0 + ah];
    short8 xa1 = *(const short8*)&Xb[(size_t)(m0 + arow) * En + k0 + ah + 8];
    float xb[16];
#pragma unroll
    for (int j = 0; j < 16; ++j)
      xb[j] = W[(size_t)(k0 + bkg + j) * En + n0 + bn];

    __syncthreads();
    *(short8*)&As[arow * 32 + ah] = xa0;
    *(short8*)&As[arow * 32 + ah + 8] = xa1;
    short8 pb0, pb1;
#pragma unroll
    for (int e = 0; e < 8; ++e) {
      pb0[e] = f2bf(xb[e]);
      pb1[e] = f2bf(xb[e + 8]);
    }
    *(short8*)&Bs[bn * 32 + bkg] = pb0;
    *(short8*)&Bs[bn * 32 + bkg + 8] = pb1;
    __syncthreads();

    short8 a[4], b[4];
#pragma unroll
    for (int i = 0; i < 4; ++i)
      a[i] = *(const short8*)&As[(wr * 64 + i * 16 + fr) * 32 + fk];
#pragma unroll
    for (int j = 0; j < 4; ++j)
      b[j] = *(const short8*)&Bs[(wc * 64 + j * 16 + fr) * 32 + fk];
#pragma unroll
    for (int i = 0; i < 4; ++i)
#pragma unroll
      for (int j = 0; j < 4; ++j)
        acc[i][j] = __builtin_amdgcn_mfma_f32_16x16x32_bf16(a[i], b[j],
                                                            acc[i][j], 0, 0, 0);
  }

  const int crow = (lane >> 4) * 4, ccol = lane & 15;
#pragma unroll
  for (int i = 0; i < 4; ++i) {
    const int m = m0 + wr * 64 + i * 16 + crow;
#pragma unroll
    for (int j = 0; j < 4; ++j) {
      const int n = n0 + wc * 64 + j * 16 + ccol;
      const float bv = bias[n];
#pragma unroll
      for (int p = 0; p < 4; ++p)
        Out[(size_t)(m + p) * En + n] = acc[i][j][p] + bv;
    }
  }
}

// ---------------- Differential flash attention: bf16 MFMA ----------------
// grid (32, 8, 2), block 256 (4 waves). QBLK=64 (16 rows/wave), KVBLK=32.
// QK^T: A=Q frags (regs), B=K rows (XOR-swizzled LDS). Softmax in C/D layout
// via 16-lane shfl groups. P -> per-wave LDS [t][s] bf16. PV: O^T = V^T * P
// (A=V^T rows from transposed-V LDS, B=P cols). Per-lane t = lane&15.
__global__ __launch_bounds__(256)
void diff_attn_mfma(const short* __restrict__ Qg, const short* __restrict__ Kg,
                    const short* __restrict__ Vtg,
                    const float* __restrict__ lq1, const float* __restrict__ lk1,
                    const float* __restrict__ lq2, const float* __restrict__ lk2,
                    short* __restrict__ ctxb) {
  __shared__ short KsL[32 * 128];      // [s][d], 16B chunks XOR-swizzled by s&7
  __shared__ short VtL[128 * 40];      // [d][s], rows padded to 40
  __shared__ short Pl[4][2][16 * 40];  // per wave, per stream: [t][s] pad 40
  __shared__ float rowstat[4][2][16];  // per wave: f (then l) per row

  const int qi = (int)gridDim.x - 1 - (int)blockIdx.x;  // heavy blocks first
  const int h = blockIdx.y, b = blockIdx.z;
  const int q0 = qi * 64;
  const int tid = threadIdx.x;
  const int lane = tid & 63;
  const int w = tid >> 6;
  const int fr = lane & 15, hi = lane >> 4;
  const size_t basebh = (size_t)(b * Hn + h) * Tn * 128;

  float lbd;
  {
    float d1 = 0.f, d2 = 0.f;
    for (int d = 0; d < 64; ++d) {
      d1 += lq1[h * 64 + d] * lk1[h * 64 + d];
      d2 += lq2[h * 64 + d] * lk2[h * 64 + d];
    }
    lbd = __expf(d1) - __expf(d2) + LAMBDA_INIT;
  }

  // Q fragments for this wave's 16 rows, held in regs for the whole block
  short8 qf[2][2];
  {
    const short* qp = Qg + basebh + (size_t)(q0 + w * 16 + fr) * 128;
#pragma unroll
    for (int st = 0; st < 2; ++st)
#pragma unroll
      for (int kp = 0; kp < 2; ++kp)
        qf[st][kp] = *(const short8*)(qp + st * 64 + kp * 32 + hi * 8);
  }

  f32x4 o1[8] = {}, o2[8] = {};
  float m1[4], l1[4], m2[4], l2[4];
#pragma unroll
  for (int p = 0; p < 4; ++p) {
    m1[p] = -1e30f; m2[p] = -1e30f; l1[p] = 0.f; l2[p] = 0.f;
  }

  const int ks_s = tid >> 3, ks_c = (tid & 7) * 2;
  const int vt_d = tid >> 1, vt_h = tid & 1;
  const short* kgb = Kg + basebh;
  const short* vgb = Vtg + (size_t)(b * Hn + h) * 128 * Tn;

  const int nkt = min(2 * qi + 3, Tn / 32);
  for (int kt = 0; kt < nkt; ++kt) {
    const int s0 = kt * 32;
    __syncthreads();  // everyone done with prev tile's KsL/VtL
    {
      const short* kr = kgb + (size_t)(s0 + ks_s) * 128;
      short8 ka = *(const short8*)(kr + ks_c * 8);
      short8 kc = *(const short8*)(kr + ks_c * 8 + 8);
      *(short8*)&KsL[ks_s * 128 + (ks_c ^ (ks_s & 7)) * 8] = ka;
      *(short8*)&KsL[ks_s * 128 + ((ks_c + 1) ^ (ks_s & 7)) * 8] = kc;
      const short* vr = vgb + (size_t)vt_d * Tn + s0 + vt_h * 16;
      short8 v0 = *(const short8*)(vr);
      short8 v1 = *(const short8*)(vr + 8);
      *(short8*)&VtL[vt_d * 40 + vt_h * 16] = v0;
      *(short8*)&VtL[vt_d * 40 + vt_h * 16 + 8] = v1;
    }
    __syncthreads();

    // ---- QK^T: S[t][s] per wave, 2 streams x 2 sblk
    f32x4 s1[2] = {}, s2[2] = {};
#pragma unroll
    for (int sb = 0; sb < 2; ++sb) {
      const int srow = sb * 16 + fr;
      const int rb = srow * 128;
      const int sw = srow & 7;
#pragma unroll
      for (int kp = 0; kp < 2; ++kp) {
        short8 kb1 = *(const short8*)&KsL[rb + ((kp * 4 + hi) ^ sw) * 8];
        short8 kb2 = *(const short8*)&KsL[rb + ((8 + kp * 4 + hi) ^ sw) * 8];
        s1[sb] = __builtin_amdgcn_mfma_f32_16x16x32_bf16(qf[0][kp], kb1,
                                                         s1[sb], 0, 0, 0);
        s2[sb] = __builtin_amdgcn_mfma_f32_16x16x32_bf16(qf[1][kp], kb2,
                                                         s2[sb], 0, 0, 0);
      }
    }

    // ---- mask + scale (t = tbase+p, s = s0+sb*16+fr)
    const int tbase = q0 + w * 16 + hi * 4;
#pragma unroll
    for (int sb = 0; sb < 2; ++sb) {
      const int sg = s0 + sb * 16 + fr;
#pragma unroll
      for (int p = 0; p < 4; ++p) {
        const bool ok = (sg <= tbase + p + 1);
        s1[sb][p] = ok ? s1[sb][p] * 0.125f : -1e30f;
        s2[sb][p] = ok ? s2[sb][p] * 0.125f : -1e30f;
      }
    }

    // ---- row reductions across the 16-lane group
    float mt1[4], mt2[4];
#pragma unroll
    for (int p = 0; p < 4; ++p) {
      mt1[p] = fmaxf(s1[0][p], s1[1][p]);
      mt2[p] = fmaxf(s2[0][p], s2[1][p]);
    }
#pragma unroll
    for (int off = 1; off <= 8; off <<= 1) {
#pragma unroll
      for (int p = 0; p < 4; ++p) {
        mt1[p] = fmaxf(mt1[p], __shfl_xor(mt1[p], off));
        mt2[p] = fmaxf(mt2[p], __shfl_xor(mt2[p], off));
      }
    }
    float f1[4], f2[4], rs1[4], rs2[4];
#pragma unroll
    for (int p = 0; p < 4; ++p) {
      const float m1n = fmaxf(m1[p], mt1[p]);
      const float m2n = fmaxf(m2[p], mt2[p]);
      f1[p] = __expf(m1[p] - m1n);
      f2[p] = __expf(m2[p] - m2n);
      m1[p] = m1n; m2[p] = m2n;
      rs1[p] = 0.f; rs2[p] = 0.f;
#pragma unroll
      for (int sb = 0; sb < 2; ++sb) {
        const float pv1 = __expf(s1[sb][p] - m1n);
        const float pv2 = __expf(s2[sb][p] - m2n);
        const short pb1 = f2bf(pv1), pb2 = f2bf(pv2);
        Pl[w][0][(hi * 4 + p) * 40 + sb * 16 + fr] = pb1;
        Pl[w][1][(hi * 4 + p) * 40 + sb * 16 + fr] = pb2;
        rs1[p] += bf2f(pb1);
        rs2[p] += bf2f(pb2);
      }
    }
#pragma unroll
    for (int off = 1; off <= 8; off <<= 1) {
#pragma unroll
      for (int p = 0; p < 4; ++p) {
        rs1[p] += __shfl_xor(rs1[p], off);
        rs2[p] += __shfl_xor(rs2[p], off);
      }
    }
#pragma unroll
    for (int p = 0; p < 4; ++p) {
      l1[p] = l1[p] * f1[p] + rs1[p];
      l2[p] = l2[p] * f2[p] + rs2[p];
      if (fr == p) {
        rowstat[w][0][hi * 4 + p] = f1[p];
        rowstat[w][1][hi * 4 + p] = f2[p];
      }
    }
    // per-lane rescale factors for its O^T column t = fr (same-wave LDS)
    const float fo1 = rowstat[w][0][fr];
    const float fo2 = rowstat[w][1][fr];

    // ---- PV: O^T += V^T * P
    const short8 pfrag1 = *(const short8*)&Pl[w][0][fr * 40 + hi * 8];
    const short8 pfrag2 = *(const short8*)&Pl[w][1][fr * 40 + hi * 8];
#pragma unroll
    for (int dblk = 0; dblk < 8; ++dblk) {
      const short8 va = *(const short8*)&VtL[(dblk * 16 + fr) * 40 + hi * 8];
#pragma unroll
      for (int e = 0; e < 4; ++e) { o1[dblk][e] *= fo1; o2[dblk][e] *= fo2; }
      o1[dblk] = __builtin_amdgcn_mfma_f32_16x16x32_bf16(va, pfrag1,
                                                         o1[dblk], 0, 0, 0);
      o2[dblk] = __builtin_amdgcn_mfma_f32_16x16x32_bf16(va, pfrag2,
                                                         o2[dblk], 0, 0, 0);
    }
  }

  // ---- epilogue: redistribute l, combine streams, store bf16 ctx
#pragma unroll
  for (int p = 0; p < 4; ++p)
    if (fr == p) {
      rowstat[w][0][hi * 4 + p] = l1[p];
      rowstat[w][1][hi * 4 + p] = l2[p];
    }
  const float lr1 = rowstat[w][0][fr];
  const float lr2 = rowstat[w][1][fr];
  const float c1 = (1.0f - LAMBDA_INIT) / lr1;
  const float c2 = (1.0f - LAMBDA_INIT) * lbd / lr2;
  const int t = q0 + w * 16 + fr;
  short* dst = ctxb + ((size_t)b * Tn + t) * En + h * 128;
#pragma unroll
  for (int dblk = 0; dblk < 8; ++dblk) {
    s16x4 pk;
#pragma unroll
    for (int e = 0; e < 4; ++e)
      pk[e] = f2bf(c1 * o1[dblk][e] - c2 * o2[dblk][e]);
    *(s16x4*)&dst[dblk * 16 + hi * 4] = pk;
  }
}

extern "C" void kernel_launch(void* const* d_in, const int* in_sizes, int n_in,
                              void* d_out, int out_size, void* d_ws, size_t ws_size,
                              hipStream_t stream) {
  const float* q   = (const float*)d_in[0];
  const float* k   = (const float*)d_in[1];
  const float* v   = (const float*)d_in[2];
  const float* Wq  = (const float*)d_in[3];
  const float* Wk  = (const float*)d_in[4];
  const float* Wv  = (const float*)d_in[5];
  const float* lq1 = (const float*)d_in[6];
  const float* lk1 = (const float*)d_in[7];
  const float* lq2 = (const float*)d_in[8];
  const float* lk2 = (const float*)d_in[9];
  const float* Wp  = (const float*)d_in[10];
  const float* bp  = (const float*)d_in[11];

  short* ws = (short*)d_ws;
  const size_t SZ = (size_t)2 * Hn * Tn * 128;  // 4,194,304 elements
  short* Qb   = ws;
  short* Kb   = ws + SZ;
  short* Vtb  = ws + 2 * SZ;
  short* ctxb = ws + 3 * SZ;

  dim3 blk(256);
  qkv_mfma<<<dim3(32, 8, 3), blk, 0, stream>>>(q, k, v, Wq, Wk, Wv,
                                               Qb, Kb, Vtb);
  diff_attn_mfma<<<dim3(32, 8, 2), blk, 0, stream>>>(Qb, Kb, Vtb,
                                                     lq1, lk1, lq2, lk2, ctxb);
  proj_mfma<<<dim3(32, 8), blk, 0, stream>>>(ctxb, Wp, bp, (float*)d_out);
}